// Round 9
// baseline (201.372 us; speedup 1.0000x reference)
//
#include <hip/hip_runtime.h>

#define BB 4
#define CH 64
#define HW 65536
#define NN 16384
#define NT 128
#define TW 256
#define XPITCH 72
#define F2PITCH 72
#define W1OFS 0
#define W2OFS 4096
#define W3OFS 8192
#define WFOFS 12288
#define FWS_BYTE 46080
#define PTAB_BYTE 49152
#define PT_ROW 160
#define WS_NEED ((size_t)PTAB_BYTE + (size_t)BB * NN * PT_ROW)

typedef __attribute__((ext_vector_type(8))) short short8;
typedef __attribute__((ext_vector_type(4))) float f32x4;

union frag_u { unsigned short u[8]; short8 v; };
union frag2_u { unsigned short u[8]; unsigned int d[4]; short8 v; };
union row_u  { uint4 q[4]; unsigned short u[32]; };
union half_u { uint4 q[2]; unsigned short u[16]; };

static __device__ __forceinline__ unsigned short f2bf(float x) {
    unsigned int u = __float_as_uint(x);
    return (unsigned short)((u + 0x7fffu + ((u >> 16) & 1u)) >> 16);
}
static __device__ __forceinline__ float bf2f(unsigned short h) {
    return __uint_as_float(((unsigned int)h) << 16);
}
// packed f32->2xbf16 RTNE (identical rounding to f2bf)
static __device__ __forceinline__ unsigned int cvtpk(float a, float b) {
    unsigned int r;
    asm("v_cvt_pk_bf16_f32 %0, %1, %2" : "=v"(r) : "v"(a), "v"(b));
    return r;
}

// ---------------- merged prepass: weights (blocks >= NN/64) + point table ----------------
// fws layout (f32): 0 b1 | 64 b2 | 128 b3 | 192 bf | 256 w_ox | 320 w_oy |
//                   384 w_corr | 448 w_fx | 512 w_fy
__global__ __launch_bounds__(256) void prep(
    const float* __restrict__ xy, const float* __restrict__ f3d,
    const float* __restrict__ lf3d,
    const float* __restrict__ w1, const float* __restrict__ b1,
    const float* __restrict__ w2, const float* __restrict__ b2,
    const float* __restrict__ w3, const float* __restrict__ b3,
    const float* __restrict__ wf, const float* __restrict__ bf,
    unsigned short* __restrict__ wpk, float* __restrict__ fws,
    char* __restrict__ pt)
{
    const int t = threadIdx.x;
    const int bx = blockIdx.x;
    if (bx >= NN / 64) {
        if (blockIdx.y != 0) return;
        const int blk = bx - NN / 64;
        if (blk == 0) {
            for (int i = t; i < 64 * 64; i += 256) {
                const int m = i >> 6, k = i & 63;
                wpk[W1OFS + i] = f2bf(w1[m * 69 + 3 + k]);
            }
        } else if (blk == 1) {
            for (int i = t; i < 64 * 64; i += 256) wpk[W2OFS + i] = f2bf(w2[i]);
        } else if (blk == 2) {
            for (int i = t; i < 64 * 64; i += 256) wpk[W3OFS + i] = f2bf(w3[i]);
        } else if (blk == 3) {
            for (int i = t; i < 64 * 128; i += 256) wpk[WFOFS + i] = f2bf(wf[i]);
        } else if (t < 64) {
            fws[t]       = b1[t];
            fws[64 + t]  = b2[t];
            fws[128 + t] = b3[t];
            fws[192 + t] = bf[t];
            fws[256 + t] = w1[t * 69 + 1];   // offset-x column (f32 path)
            fws[320 + t] = w1[t * 69 + 2];   // offset-y column
            fws[384 + t] = w1[t * 69 + 0];   // corr column
            fws[448 + t] = w1[t * 69 + 67];  // flow-x column
            fws[512 + t] = w1[t * 69 + 68];  // flow-y column
        }
        return;
    }
    const int cq = t >> 6;
    const int l = t & 63;
    const int gn = bx * 64 + l;
    const int b = blockIdx.y;
    half_u r;
#pragma unroll
    for (int i = 0; i < 16; i++)
        r.u[i] = f2bf(f3d[(size_t)(b * CH + cq * 16 + i) * NN + gn]);
    char* row = pt + ((size_t)b * NN + gn) * PT_ROW;
    uint4* rq = (uint4*)row;
    rq[2 * cq] = r.q[0];
    rq[2 * cq + 1] = r.q[1];
    if (cq == 0) {
        float4 e;
        e.x = xy[(size_t)(b * 2 + 0) * NN + gn];
        e.y = xy[(size_t)(b * 2 + 1) * NN + gn];
        e.z = lf3d[(size_t)(b * 2 + 0) * NN + gn];
        e.w = lf3d[(size_t)(b * 2 + 1) * NN + gn];
        *(float4*)(row + 144) = e;
    }
}

// ---------------- weight staging: global wpk -> LDS, XOR-swizzled rows ----------------
// layout: W1@0, W2@4096, W3@8192 ([64][64], row=128B), WF@12288 ([64][128], row=256B)
// byte addr = base + row*RB + (colbyte ^ ((row&7)<<4)); bijective per row, kills the
// 16-way bank conflict of stride-128B row-major ds_read_b128 (G4 / T2).
static __device__ __forceinline__ void wstage(
    const unsigned short* __restrict__ wpk, unsigned short* wl, int tid)
{
#pragma unroll 1
    for (int m = 0; m < 3; m++) {
        const char* g = (const char*)(wpk + m * 4096);
        char* l = (char*)(wl + m * 4096);
        for (int i = tid; i < 512; i += 256) {   // 64 rows x 8 16B-chunks
            const int row = i >> 3, cb = (i & 7) * 16;
            const uint4 v = *(const uint4*)(g + row * 128 + cb);
            *(uint4*)(l + row * 128 + (cb ^ ((row & 7) << 4))) = v;
        }
    }
    {
        const char* g = (const char*)(wpk + WFOFS);
        char* l = (char*)(wl + WFOFS);
        for (int i = tid; i < 1024; i += 256) {  // 64 rows x 16 16B-chunks
            const int row = i >> 4, cb = (i & 15) * 16;
            const uint4 v = *(const uint4*)(g + row * 256 + cb);
            *(uint4*)(l + row * 256 + (cb ^ ((row & 7) << 4))) = v;
        }
    }
}

// ---------------- per-tile prefetch register set ----------------
struct pref_t {
    float4 fv[8];   // feat2d tile slice (8 channels x 4 px)
    row_u g;        // gathered 3D feature half-row (32 bf16)
    float4 e;       // xy / lf3d extras (cp==0 lanes)
    float lfx, lfy; // lf2d at pixel (cp==0 lanes)
};

static __device__ __forceinline__ void tile_load(
    pref_t& P, const float* __restrict__ feat2d, const float* __restrict__ lf2d,
    const char* __restrict__ ptab, int b, int p_base, int w, int lane, int idx)
{
    const int ci = lane >> 3, qd = lane & 7;
    const int px0 = 32 * w + qd * 4;
#pragma unroll
    for (int cc = 0; cc < 8; cc++)
        P.fv[cc] = *(const float4*)(feat2d + (size_t)(b * CH + ci * 8 + cc) * HW + p_base + px0);
    const int cp = lane >> 5, j = lane & 31;
    const int n = 32 * w + j;
    const char* prow = ptab + ((size_t)b * NN + idx) * PT_ROW;
#pragma unroll
    for (int k = 0; k < 4; k++) P.g.q[k] = ((const uint4*)prow)[cp * 4 + k];
    if (cp == 0) {
        P.e = *(const float4*)(prow + 144);
        P.lfx = lf2d[(size_t)(b * 2 + 0) * HW + p_base + n];
        P.lfy = lf2d[(size_t)(b * 2 + 1) * HW + p_base + n];
    }
}

static __device__ __forceinline__ void tile_stage(
    const pref_t& P, unsigned short* F2, unsigned short* Xhi, int w, int lane)
{
    const int ci = lane >> 3, qd = lane & 7;
    const int px0 = 32 * w + qd * 4;
#pragma unroll
    for (int px = 0; px < 4; px++) {
        frag2_u fr;
#pragma unroll
        for (int cc = 0; cc < 4; cc++)
            fr.d[cc] = cvtpk(((const float*)&P.fv[2 * cc])[px], ((const float*)&P.fv[2 * cc + 1])[px]);
        *(short8*)&F2[(px0 + px) * F2PITCH + ci * 8] = fr.v;
    }
    const int cp = lane >> 5, j = lane & 31;
    const int n = 32 * w + j;
    uint4* xp = (uint4*)&Xhi[n * XPITCH + cp * 32];
#pragma unroll
    for (int k = 0; k < 4; k++) xp[k] = P.g.q[k];
}

static __device__ __forceinline__ void tile_corr(
    const pref_t& P, const unsigned short* F2, float* offsS, float* auxS,
    int p_base, int w, int lane)
{
    const int cp = lane >> 5, j = lane & 31;
    const int n = 32 * w + j;
    const int p = p_base + n;
    frag_u f2v[4];
#pragma unroll
    for (int k = 0; k < 4; k++)
        f2v[k].v = *(const short8*)&F2[n * F2PITCH + cp * 32 + k * 8];
    float ca = 0.f;
#pragma unroll
    for (int i = 0; i < 32; i++)
        ca += bf2f(f2v[i >> 3].u[i & 7]) * bf2f(P.g.u[i]);
    ca += __shfl_xor(ca, 32);
    if (cp == 0) {
        offsS[n] = P.e.x - (float)(p & 255);
        offsS[NT + n] = P.e.y - (float)(p >> 8);
        auxS[n] = ca * (1.0f / 64.0f);
        auxS[NT + n] = P.e.z - P.lfx;
        auxS[2 * NT + n] = P.e.w - P.lfy;
    }
}

// ---------------- L1 MFMA (A from LDS weights swizzled, B from LDS Xhi, hi only) ----------
static __device__ __forceinline__ void layer_l1(
    const unsigned short* wrow, const unsigned short* Xh,
    int w, int ln, int q, int swz, f32x4 acc[4][2])
{
#pragma unroll
    for (int kt = 0; kt < 2; kt++) {
        const int kb = (kt * 32 + q * 8) * 2;
        short8 A[4];
#pragma unroll
        for (int mi = 0; mi < 4; mi++)
            A[mi] = *(const short8*)((const char*)wrow + (mi * 16 + ln) * 128 + (kb ^ swz));
#pragma unroll
        for (int ni = 0; ni < 2; ni++) {
            const int nr = 32 * w + ni * 16 + ln;
            short8 bh = *(const short8*)(Xh + nr * XPITCH + kt * 32 + q * 8);
            __builtin_amdgcn_s_setprio(1);
#pragma unroll
            for (int mi = 0; mi < 4; mi++)
                acc[mi][ni] = __builtin_amdgcn_mfma_f32_16x16x32_bf16(A[mi], bh, acc[mi][ni], 0, 0, 0);
            __builtin_amdgcn_s_setprio(0);
        }
    }
}

// ---------------- reg-exchange layer: A from LDS weights, B via ds_bpermute ----------------
// lane (q,ln) target u32 p of B(kt,ni) = pk[mi=kt*2+(q>>1)][ni][t=p&1]
// pulled from lane ((q&1)*2+(p>>1))*16+ln
template<int RB>   // weight row bytes (128 or 256)
static __device__ __forceinline__ void layer_reg(
    const unsigned short* wrow,
    const unsigned int pkH[4][2][2], const unsigned int pkL[4][2][2],
    int srcA, int srcB, int qh, int ln, int q, int swz, f32x4 acc[4][2])
{
#pragma unroll
    for (int kt = 0; kt < 2; kt++) {
        const int kb = (kt * 32 + q * 8) * 2;
        short8 A[4];
#pragma unroll
        for (int mi = 0; mi < 4; mi++)
            A[mi] = *(const short8*)((const char*)wrow + (mi * 16 + ln) * RB + (kb ^ swz));
#pragma unroll
        for (int ni = 0; ni < 2; ni++) {
            frag2_u bh, bl;
#pragma unroll
            for (int p = 0; p < 4; p++) {
                const int src = (p >> 1) ? srcB : srcA;
                const unsigned h0 = (unsigned)__builtin_amdgcn_ds_bpermute(src, (int)pkH[kt * 2 + 0][ni][p & 1]);
                const unsigned h1 = (unsigned)__builtin_amdgcn_ds_bpermute(src, (int)pkH[kt * 2 + 1][ni][p & 1]);
                bh.d[p] = qh ? h1 : h0;
                const unsigned l0 = (unsigned)__builtin_amdgcn_ds_bpermute(src, (int)pkL[kt * 2 + 0][ni][p & 1]);
                const unsigned l1 = (unsigned)__builtin_amdgcn_ds_bpermute(src, (int)pkL[kt * 2 + 1][ni][p & 1]);
                bl.d[p] = qh ? l1 : l0;
            }
            __builtin_amdgcn_s_setprio(1);
#pragma unroll
            for (int mi = 0; mi < 4; mi++) {
                acc[mi][ni] = __builtin_amdgcn_mfma_f32_16x16x32_bf16(A[mi], bh.v, acc[mi][ni], 0, 0, 0);
                acc[mi][ni] = __builtin_amdgcn_mfma_f32_16x16x32_bf16(A[mi], bl.v, acc[mi][ni], 0, 0, 0);
            }
            __builtin_amdgcn_s_setprio(0);
        }
    }
}

static __device__ __forceinline__ void zero_acc(f32x4 acc[4][2]) {
#pragma unroll
    for (int mi = 0; mi < 4; mi++)
#pragma unroll
        for (int ni = 0; ni < 2; ni++)
#pragma unroll
            for (int r = 0; r < 4; r++) acc[mi][ni][r] = 0.f;
}

// epilogue: leaky(acc + bias [+ rank-5 f32 fix]) -> packed bf16 hi/lo rails in registers
static __device__ __forceinline__ void epi_pack(
    f32x4 acc[4][2], const float* __restrict__ fws, int bofs, bool off_fix,
    const float* offsp, const float* auxp,
    unsigned int pkH[4][2][2], unsigned int pkL[4][2][2],
    int w, int ln, int q)
{
#pragma unroll
    for (int mi = 0; mi < 4; mi++) {
        const float4 bias = *(const float4*)(fws + bofs + mi * 16 + q * 4);
        float4 wox = bias, woy = bias, wco = bias, wfx = bias, wfy = bias;
        if (off_fix) {
            wox = *(const float4*)(fws + 256 + mi * 16 + q * 4);
            woy = *(const float4*)(fws + 320 + mi * 16 + q * 4);
            wco = *(const float4*)(fws + 384 + mi * 16 + q * 4);
            wfx = *(const float4*)(fws + 448 + mi * 16 + q * 4);
            wfy = *(const float4*)(fws + 512 + mi * 16 + q * 4);
        }
#pragma unroll
        for (int ni = 0; ni < 2; ni++) {
            const int nr = 32 * w + ni * 16 + ln;
            float ox = 0.f, oy = 0.f, co = 0.f, fx = 0.f, fy = 0.f;
            if (off_fix) {
                ox = offsp[nr]; oy = offsp[NT + nr];
                co = auxp[nr];  fx = auxp[NT + nr]; fy = auxp[2 * NT + nr];
            }
            float av[4];
#pragma unroll
            for (int r = 0; r < 4; r++) {
                float a = acc[mi][ni][r] + ((const float*)&bias)[r];
                if (off_fix) {
                    a += ((const float*)&wox)[r] * ox + ((const float*)&woy)[r] * oy;
                    a += ((const float*)&wco)[r] * co;
                    a += ((const float*)&wfx)[r] * fx + ((const float*)&wfy)[r] * fy;
                }
                av[r] = fmaxf(a, 0.1f * a);
            }
#pragma unroll
            for (int t = 0; t < 2; t++) {
                const unsigned hh = cvtpk(av[2 * t], av[2 * t + 1]);
                const float l0 = av[2 * t]     - __uint_as_float(hh << 16);
                const float l1 = av[2 * t + 1] - __uint_as_float(hh & 0xffff0000u);
                pkH[mi][ni][t] = hh;
                pkL[mi][ni][t] = cvtpk(l0, l1);
            }
        }
    }
}

// ---------------- main fused kernel: rolled 2-tile loop + rolled L2/L3 ------------------
// Same math/data-paths as R8; control flow rolled to shrink code footprint ~2.5x so the
// body fits I$ (hypothesis: time tracked instruction count at constant ~75% stall = fetch
// bound). LDS = 80,384 B -> 2 blocks/CU.
__global__ __launch_bounds__(256, 2) void fuse(
    const float* __restrict__ feat2d, const float* __restrict__ lf2d,
    const int* __restrict__ nn,
    const unsigned short* __restrict__ wpk, const float* __restrict__ fws,
    const char* __restrict__ ptab,
    float* __restrict__ out)
{
    __shared__ unsigned short Xhi[NT * XPITCH];   // 18432 B (L1 gather stage)
    __shared__ unsigned short F2[NT * F2PITCH];   // 18432 B (feat2d tile bf16)
    __shared__ unsigned short Wl[20480];          // 40960 B (all weights, swizzled)
    __shared__ float offsS[2 * NT];               //  1024 B
    __shared__ float auxS[3 * NT];                //  1536 B

    const int tid = threadIdx.x;
    const int w = tid >> 6, lane = tid & 63;
    const int q = lane >> 4, ln = lane & 15;
    const int b = blockIdx.y;
    const int p0 = blockIdx.x * TW;
    const int n = 32 * w + (lane & 31);

    // bpermute byte addresses for the q-group exchange (src lanes (q&1)*2*16+ln, +16)
    const int srcA = (((lane >> 4) & 1) * 32 + ln) * 4;
    const int srcB = srcA + 64;
    const int qh = q >> 1;
    const int swz = (ln & 7) << 4;

    const int idx0 = nn[(size_t)b * HW + p0 + n];
    const int idx1 = nn[(size_t)b * HW + p0 + NT + n];

    pref_t P, Pn;
    tile_load(P, feat2d, lf2d, ptab, b, p0, w, lane, idx0);   // HBM latency hides under wstage
    wstage(wpk, Wl, tid);
    __syncthreads();

#pragma unroll 1
    for (int t = 0; t < 2; t++) {
        const int p_base = p0 + t * NT;
        tile_stage(P, F2, Xhi, w, lane);
        if (t == 0)   // prefetch tile 1 while tile 0 computes
            tile_load(Pn, feat2d, lf2d, ptab, b, p0 + NT, w, lane, idx1);
        tile_corr(P, F2, offsS, auxS, p_base, w, lane);

        unsigned int pkH[4][2][2], pkL[4][2][2];
        f32x4 acc[4][2];
        // L1 (K=64, g only; corr/offset/flow enter via rank-5 f32 fix)
        zero_acc(acc);
        layer_l1(Wl + W1OFS, Xhi, w, ln, q, swz, acc);
        epi_pack(acc, fws, 0, true, offsS, auxS, pkH, pkL, w, ln, q);
        // L2, L3 (identical structure — rolled)
#pragma unroll 1
        for (int l = 0; l < 2; l++) {
            zero_acc(acc);
            layer_reg<128>(Wl + W2OFS + (l << 12), pkH, pkL, srcA, srcB, qh, ln, q, swz, acc);
            epi_pack(acc, fws, 64 + (l << 6), false, offsS, auxS, pkH, pkL, w, ln, q);
        }
        // Lf: k 0-63 = x3 (reg exchange, hi+lo), k 64-127 = feat2d tile (F2 LDS, hi only)
        zero_acc(acc);
        layer_reg<256>(Wl + WFOFS, pkH, pkL, srcA, srcB, qh, ln, q, swz, acc);
#pragma unroll
        for (int kt = 2; kt < 4; kt++) {
            const int kb = (kt * 32 + q * 8) * 2;
            short8 A[4];
#pragma unroll
            for (int mi = 0; mi < 4; mi++)
                A[mi] = *(const short8*)((const char*)(Wl + WFOFS) + (mi * 16 + ln) * 256 + (kb ^ swz));
#pragma unroll
            for (int ni = 0; ni < 2; ni++) {
                const int nr = 32 * w + ni * 16 + ln;
                frag_u fh;
                fh.v = *(const short8*)&F2[nr * F2PITCH + (kt - 2) * 32 + q * 8];
                __builtin_amdgcn_s_setprio(1);
#pragma unroll
                for (int mi = 0; mi < 4; mi++)
                    acc[mi][ni] = __builtin_amdgcn_mfma_f32_16x16x32_bf16(A[mi], fh.v, acc[mi][ni], 0, 0, 0);
                __builtin_amdgcn_s_setprio(0);
            }
        }
        // final epilogue -> out f32
#pragma unroll
        for (int mi = 0; mi < 4; mi++) {
            const float4 bias = *(const float4*)(fws + 192 + mi * 16 + q * 4);
#pragma unroll
            for (int ni = 0; ni < 2; ni++) {
#pragma unroll
                for (int r = 0; r < 4; r++) {
                    float a = acc[mi][ni][r] + ((const float*)&bias)[r];
                    a = fmaxf(a, 0.1f * a);
                    const int m = mi * 16 + q * 4 + r;
                    out[(size_t)(b * CH + m) * HW + p_base + 32 * w + ni * 16 + ln] = a;
                }
            }
        }
        if (t == 0) P = Pn;   // register handoff (static names — no scratch)
    }
}

// ---------------- fallback: used only if ws too small ----------------
__global__ __launch_bounds__(256) void fuse_slow(
    const float* __restrict__ feat2d, const float* __restrict__ lf2d,
    const float* __restrict__ xy, const float* __restrict__ feat3d,
    const float* __restrict__ lf3d, const int* __restrict__ nn,
    const float* __restrict__ w1, const float* __restrict__ b1,
    const float* __restrict__ w2, const float* __restrict__ b2,
    const float* __restrict__ w3, const float* __restrict__ b3,
    const float* __restrict__ wf, const float* __restrict__ bfv,
    float* __restrict__ out)
{
    const int p = blockIdx.x * 256 + threadIdx.x;
    const int b = blockIdx.y;
    const int idx = nn[(size_t)b * HW + p];
    const float* f3 = feat3d + (size_t)b * CH * NN + idx;
    float g[CH];
#pragma unroll
    for (int c = 0; c < CH; c++) g[c] = f3[(size_t)c * NN];
    const float fl3x = lf3d[(size_t)(b * 2 + 0) * NN + idx];
    const float fl3y = lf3d[(size_t)(b * 2 + 1) * NN + idx];
    const float xyx = xy[(size_t)(b * 2 + 0) * NN + idx];
    const float xyy = xy[(size_t)(b * 2 + 1) * NN + idx];
    const float* f2p = feat2d + (size_t)b * CH * HW + p;
    float corr = 0.f;
#pragma unroll
    for (int c = 0; c < CH; c++) corr += f2p[(size_t)c * HW] * g[c];
    corr *= (1.f / 64.f);
    float xin[69];
    xin[0] = corr;
    xin[1] = xyx - (float)(p & 255);
    xin[2] = xyy - (float)(p >> 8);
#pragma unroll
    for (int c = 0; c < CH; c++) xin[3 + c] = g[c];
    xin[67] = fl3x - lf2d[(size_t)(b * 2 + 0) * HW + p];
    xin[68] = fl3y - lf2d[(size_t)(b * 2 + 1) * HW + p];
    float x1[64], x2[64], x3[64], accv[64];
#pragma unroll
    for (int o = 0; o < 64; o++) {
        float a = b1[o];
#pragma unroll
        for (int k = 0; k < 69; k++) a += w1[o * 69 + k] * xin[k];
        x1[o] = (a >= 0.f) ? a : 0.1f * a;
    }
#pragma unroll
    for (int o = 0; o < 64; o++) {
        float a = b2[o];
#pragma unroll
        for (int k = 0; k < 64; k++) a += w2[o * 64 + k] * x1[k];
        x2[o] = (a >= 0.f) ? a : 0.1f * a;
    }
#pragma unroll
    for (int o = 0; o < 64; o++) {
        float a = b3[o];
#pragma unroll
        for (int k = 0; k < 64; k++) a += w3[o * 64 + k] * x2[k];
        x3[o] = (a >= 0.f) ? a : 0.1f * a;
    }
#pragma unroll
    for (int o = 0; o < 64; o++) {
        float a = bfv[o];
#pragma unroll
        for (int k = 0; k < 64; k++) a += wf[o * 128 + k] * x3[k];
        accv[o] = a;
    }
#pragma unroll
    for (int k = 0; k < 64; k++) {
        const float f = f2p[(size_t)k * HW];
#pragma unroll
        for (int o = 0; o < 64; o++) accv[o] += wf[o * 128 + 64 + k] * f;
    }
#pragma unroll
    for (int o = 0; o < 64; o++) {
        float a = accv[o];
        a = (a >= 0.f) ? a : 0.1f * a;
        out[(size_t)(b * CH + o) * HW + p] = a;
    }
}

extern "C" void kernel_launch(void* const* d_in, const int* in_sizes, int n_in,
                              void* d_out, int out_size, void* d_ws, size_t ws_size,
                              hipStream_t stream)
{
    const float* xy   = (const float*)d_in[0];
    const float* f2d  = (const float*)d_in[1];
    const float* f3d  = (const float*)d_in[2];
    const float* lf2d = (const float*)d_in[3];
    const float* lf3d = (const float*)d_in[4];
    const int*   nn   = (const int*)d_in[5];
    const float* w1 = (const float*)d_in[6];
    const float* b1 = (const float*)d_in[7];
    const float* w2 = (const float*)d_in[8];
    const float* b2 = (const float*)d_in[9];
    const float* w3 = (const float*)d_in[10];
    const float* b3 = (const float*)d_in[11];
    const float* wf = (const float*)d_in[12];
    const float* bf = (const float*)d_in[13];

    if (ws_size >= WS_NEED) {
        unsigned short* wpk = (unsigned short*)d_ws;
        float* fws = (float*)((char*)d_ws + FWS_BYTE);
        char* pt = (char*)d_ws + PTAB_BYTE;
        prep<<<dim3(NN / 64 + 5, BB), 256, 0, stream>>>(xy, f3d, lf3d,
                                                        w1, b1, w2, b2, w3, b3, wf, bf,
                                                        wpk, fws, pt);
        fuse<<<dim3(HW / TW, BB), 256, 0, stream>>>(f2d, lf2d, nn, wpk, fws, pt, (float*)d_out);
    } else {
        fuse_slow<<<dim3(HW / 256, BB), 256, 0, stream>>>(f2d, lf2d, xy, f3d, lf3d, nn,
                                                          w1, b1, w2, b2, w3, b3, wf, bf,
                                                          (float*)d_out);
    }
}

// Round 10
// 201.095 us; speedup vs baseline: 1.0014x; 1.0014x over previous
//
#include <hip/hip_runtime.h>

#define BB 4
#define CH 64
#define HW 65536
#define NN 16384
#define NT 128
#define F2PITCH 72
#define W1OFS 0
#define W2OFS 4096
#define W3OFS 8192
#define WFOFS 12288
#define W2L 0
#define W3L 4096
#define WFL 8192
#define FWS_BYTE 46080
#define PTAB_BYTE 49152
#define PT_ROW 160
#define WS_NEED ((size_t)PTAB_BYTE + (size_t)BB * NN * PT_ROW)

typedef __attribute__((ext_vector_type(8))) short short8;
typedef __attribute__((ext_vector_type(4))) float f32x4;

union frag_u { unsigned short u[8]; short8 v; };
union frag2_u { unsigned short u[8]; unsigned int d[4]; short8 v; };
union bfrag { uint4 qv; short8 v; unsigned short u[8]; };
union half_u { uint4 q[2]; unsigned short u[16]; };

static __device__ __forceinline__ unsigned short f2bf(float x) {
    unsigned int u = __float_as_uint(x);
    return (unsigned short)((u + 0x7fffu + ((u >> 16) & 1u)) >> 16);
}
static __device__ __forceinline__ float bf2f(unsigned short h) {
    return __uint_as_float(((unsigned int)h) << 16);
}
// packed f32->2xbf16 RTNE (identical rounding to f2bf)
static __device__ __forceinline__ unsigned int cvtpk(float a, float b) {
    unsigned int r;
    asm("v_cvt_pk_bf16_f32 %0, %1, %2" : "=v"(r) : "v"(a), "v"(b));
    return r;
}

// ---------------- merged prepass: weights (blocks >= NN/64) + point table ----------------
// fws layout (f32): 0 b1 | 64 b2 | 128 b3 | 192 bf | 256 w_ox | 320 w_oy |
//                   384 w_corr | 448 w_fx | 512 w_fy
__global__ __launch_bounds__(256) void prep(
    const float* __restrict__ xy, const float* __restrict__ f3d,
    const float* __restrict__ lf3d,
    const float* __restrict__ w1, const float* __restrict__ b1,
    const float* __restrict__ w2, const float* __restrict__ b2,
    const float* __restrict__ w3, const float* __restrict__ b3,
    const float* __restrict__ wf, const float* __restrict__ bf,
    unsigned short* __restrict__ wpk, float* __restrict__ fws,
    char* __restrict__ pt)
{
    const int t = threadIdx.x;
    const int bx = blockIdx.x;
    if (bx >= NN / 64) {
        if (blockIdx.y != 0) return;
        const int blk = bx - NN / 64;
        if (blk == 0) {
            for (int i = t; i < 64 * 64; i += 256) {
                const int m = i >> 6, k = i & 63;
                wpk[W1OFS + i] = f2bf(w1[m * 69 + 3 + k]);
            }
        } else if (blk == 1) {
            for (int i = t; i < 64 * 64; i += 256) wpk[W2OFS + i] = f2bf(w2[i]);
        } else if (blk == 2) {
            for (int i = t; i < 64 * 64; i += 256) wpk[W3OFS + i] = f2bf(w3[i]);
        } else if (blk == 3) {
            for (int i = t; i < 64 * 128; i += 256) wpk[WFOFS + i] = f2bf(wf[i]);
        } else if (t < 64) {
            fws[t]       = b1[t];
            fws[64 + t]  = b2[t];
            fws[128 + t] = b3[t];
            fws[192 + t] = bf[t];
            fws[256 + t] = w1[t * 69 + 1];   // offset-x column (f32 path)
            fws[320 + t] = w1[t * 69 + 2];   // offset-y column
            fws[384 + t] = w1[t * 69 + 0];   // corr column
            fws[448 + t] = w1[t * 69 + 67];  // flow-x column
            fws[512 + t] = w1[t * 69 + 68];  // flow-y column
        }
        return;
    }
    const int cq = t >> 6;
    const int l = t & 63;
    const int gn = bx * 64 + l;
    const int b = blockIdx.y;
    half_u r;
#pragma unroll
    for (int i = 0; i < 16; i++)
        r.u[i] = f2bf(f3d[(size_t)(b * CH + cq * 16 + i) * NN + gn]);
    char* row = pt + ((size_t)b * NN + gn) * PT_ROW;
    uint4* rq = (uint4*)row;
    rq[2 * cq] = r.q[0];
    rq[2 * cq + 1] = r.q[1];
    if (cq == 0) {
        float4 e;
        e.x = xy[(size_t)(b * 2 + 0) * NN + gn];
        e.y = xy[(size_t)(b * 2 + 1) * NN + gn];
        e.z = lf3d[(size_t)(b * 2 + 0) * NN + gn];
        e.w = lf3d[(size_t)(b * 2 + 1) * NN + gn];
        *(float4*)(row + 144) = e;
    }
}

// ---------------- weight staging: W2/W3/WF global -> LDS, XOR-swizzled rows ----------------
// LDS layout: W2@W2L ([64][64] row=128B), W3@W3L, WF@WFL ([64][128] row=256B)
// byte addr = base + row*RB + (colbyte ^ ((row&7)<<4)) — kills the 16-way bank conflict
// of stride-128/256B row-major ds_read_b128 (G4 / T2). W1 stays global (L2-hot, 8 loads/tile).
static __device__ __forceinline__ void wstage(
    const unsigned short* __restrict__ wpk, unsigned short* wl, int tid)
{
#pragma unroll 1
    for (int m = 0; m < 2; m++) {
        const char* g = (const char*)(wpk + W2OFS + m * 4096);
        char* l = (char*)(wl + m * 4096);
        for (int i = tid; i < 512; i += 256) {   // 64 rows x 8 16B-chunks
            const int row = i >> 3, cb = (i & 7) * 16;
            const uint4 v = *(const uint4*)(g + row * 128 + cb);
            *(uint4*)(l + row * 128 + (cb ^ ((row & 7) << 4))) = v;
        }
    }
    {
        const char* g = (const char*)(wpk + WFOFS);
        char* l = (char*)(wl + WFL);
        for (int i = tid; i < 1024; i += 256) {  // 64 rows x 16 16B-chunks
            const int row = i >> 4, cb = (i & 15) * 16;
            const uint4 v = *(const uint4*)(g + row * 256 + cb);
            *(uint4*)(l + row * 256 + (cb ^ ((row & 7) << 4))) = v;
        }
    }
}

// ---------------- per-tile prefetch register set ----------------
// g4[ni][kt] = ptab row(px 32w+ni*16+ln), bytes kt*64+q*16..+16  — exactly the MFMA
// B-fragment for L1 (bit-identical to the old Xhi path), so L1 needs no LDS at all.
struct pref_t {
    float4 fv[8];       // feat2d tile slice (8 channels x 4 px) — (ci,qd) mapping
    bfrag g4[2][2];     // gathered 3D rows in B-fragment layout
    float4 e;           // xy / lf3d extras (lane<32: px 32w+lane)
    float lfx, lfy;     // lf2d at that px
};

static __device__ __forceinline__ void tile_load(
    pref_t& P, const float* __restrict__ feat2d, const float* __restrict__ lf2d,
    const char* __restrict__ ptab, int b, int p_base, int w, int lane,
    int i0, int i1)
{
    const int ci = lane >> 3, qd = lane & 7;
    const int px0 = 32 * w + qd * 4;
#pragma unroll
    for (int cc = 0; cc < 8; cc++)
        P.fv[cc] = *(const float4*)(feat2d + (size_t)(b * CH + ci * 8 + cc) * HW + p_base + px0);
    const int q = lane >> 4;
    const uint4* r0 = (const uint4*)(ptab + ((size_t)b * NN + i0) * PT_ROW);
    const uint4* r1 = (const uint4*)(ptab + ((size_t)b * NN + i1) * PT_ROW);
#pragma unroll
    for (int kt = 0; kt < 2; kt++) {
        P.g4[0][kt].qv = r0[kt * 4 + (q & 3)];
        P.g4[1][kt].qv = r1[kt * 4 + (q & 3)];
    }
    if (lane < 32) {
        const char* re = (const char*)(lane >= 16 ? r1 : r0);
        P.e = *(const float4*)(re + 144);
        P.lfx = lf2d[(size_t)(b * 2 + 0) * HW + p_base + 32 * w + lane];
        P.lfy = lf2d[(size_t)(b * 2 + 1) * HW + p_base + 32 * w + lane];
    }
}

static __device__ __forceinline__ void tile_stage(
    const pref_t& P, unsigned short* F2, int w, int lane)
{
    const int ci = lane >> 3, qd = lane & 7;
    const int px0 = 32 * w + qd * 4;
#pragma unroll
    for (int px = 0; px < 4; px++) {
        frag2_u fr;
#pragma unroll
        for (int cc = 0; cc < 4; cc++)
            fr.d[cc] = cvtpk(((const float*)&P.fv[2 * cc])[px], ((const float*)&P.fv[2 * cc + 1])[px]);
        *(short8*)&F2[(px0 + px) * F2PITCH + ci * 8] = fr.v;
    }
}

// corr in fragment layout: lane (q,ln) covers ch {kt*32+q*8..+8} of its 2 px; reduce over
// the 4 q-groups with 2 shfl_xor. Writes offs/aux for px 32w+lane (lane<32).
static __device__ __forceinline__ void tile_corr(
    const pref_t& P, const unsigned short* F2, float* offsS, float* auxS,
    int p_base, int w, int lane, int q, int ln)
{
    float ca0 = 0.f, ca1 = 0.f;
#pragma unroll
    for (int kt = 0; kt < 2; kt++) {
        frag_u f0, f1;
        f0.v = *(const short8*)&F2[(32 * w + ln) * F2PITCH + kt * 32 + q * 8];
        f1.v = *(const short8*)&F2[(32 * w + 16 + ln) * F2PITCH + kt * 32 + q * 8];
#pragma unroll
        for (int j = 0; j < 8; j++) {
            ca0 += bf2f(f0.u[j]) * bf2f(P.g4[0][kt].u[j]);
            ca1 += bf2f(f1.u[j]) * bf2f(P.g4[1][kt].u[j]);
        }
    }
    ca0 += __shfl_xor(ca0, 16); ca0 += __shfl_xor(ca0, 32);
    ca1 += __shfl_xor(ca1, 16); ca1 += __shfl_xor(ca1, 32);
    if (lane < 32) {
        const int n = 32 * w + lane;
        const int p = p_base + n;
        offsS[n] = P.e.x - (float)(p & 255);
        offsS[NT + n] = P.e.y - (float)(p >> 8);
        auxS[n] = (lane >= 16 ? ca1 : ca0) * (1.0f / 64.0f);
        auxS[NT + n] = P.e.z - P.lfx;
        auxS[2 * NT + n] = P.e.w - P.lfy;
    }
}

// ---------------- reg-exchange layer: A from LDS weights, B via ds_bpermute ----------------
// lane (q,ln) target u32 p of B(kt,ni) = pk[mi=kt*2+(q>>1)][ni][t=p&1]
// pulled from lane ((q&1)*2+(p>>1))*16+ln
template<int RB>   // weight row bytes (128 or 256)
static __device__ __forceinline__ void layer_reg(
    const unsigned short* wrow,
    const unsigned int pkH[4][2][2], const unsigned int pkL[4][2][2],
    int srcA, int srcB, int qh, int ln, int q, int swz, f32x4 acc[4][2])
{
#pragma unroll
    for (int kt = 0; kt < 2; kt++) {
        const int kb = (kt * 32 + q * 8) * 2;
        short8 A[4];
#pragma unroll
        for (int mi = 0; mi < 4; mi++)
            A[mi] = *(const short8*)((const char*)wrow + (mi * 16 + ln) * RB + (kb ^ swz));
#pragma unroll
        for (int ni = 0; ni < 2; ni++) {
            frag2_u bh, bl;
#pragma unroll
            for (int p = 0; p < 4; p++) {
                const int src = (p >> 1) ? srcB : srcA;
                const unsigned h0 = (unsigned)__builtin_amdgcn_ds_bpermute(src, (int)pkH[kt * 2 + 0][ni][p & 1]);
                const unsigned h1 = (unsigned)__builtin_amdgcn_ds_bpermute(src, (int)pkH[kt * 2 + 1][ni][p & 1]);
                bh.d[p] = qh ? h1 : h0;
                const unsigned l0 = (unsigned)__builtin_amdgcn_ds_bpermute(src, (int)pkL[kt * 2 + 0][ni][p & 1]);
                const unsigned l1 = (unsigned)__builtin_amdgcn_ds_bpermute(src, (int)pkL[kt * 2 + 1][ni][p & 1]);
                bl.d[p] = qh ? l1 : l0;
            }
            __builtin_amdgcn_s_setprio(1);
#pragma unroll
            for (int mi = 0; mi < 4; mi++) {
                acc[mi][ni] = __builtin_amdgcn_mfma_f32_16x16x32_bf16(A[mi], bh.v, acc[mi][ni], 0, 0, 0);
                acc[mi][ni] = __builtin_amdgcn_mfma_f32_16x16x32_bf16(A[mi], bl.v, acc[mi][ni], 0, 0, 0);
            }
            __builtin_amdgcn_s_setprio(0);
        }
    }
}

static __device__ __forceinline__ void zero_acc(f32x4 acc[4][2]) {
#pragma unroll
    for (int mi = 0; mi < 4; mi++)
#pragma unroll
        for (int ni = 0; ni < 2; ni++)
#pragma unroll
            for (int r = 0; r < 4; r++) acc[mi][ni][r] = 0.f;
}

// epilogue: leaky(acc + bias [+ rank-5 f32 fix]) -> packed bf16 hi/lo rails in registers
static __device__ __forceinline__ void epi_pack(
    f32x4 acc[4][2], const float* __restrict__ fws, int bofs, bool off_fix,
    const float* offsp, const float* auxp,
    unsigned int pkH[4][2][2], unsigned int pkL[4][2][2],
    int w, int ln, int q)
{
#pragma unroll
    for (int mi = 0; mi < 4; mi++) {
        const float4 bias = *(const float4*)(fws + bofs + mi * 16 + q * 4);
        float4 wox = bias, woy = bias, wco = bias, wfx = bias, wfy = bias;
        if (off_fix) {
            wox = *(const float4*)(fws + 256 + mi * 16 + q * 4);
            woy = *(const float4*)(fws + 320 + mi * 16 + q * 4);
            wco = *(const float4*)(fws + 384 + mi * 16 + q * 4);
            wfx = *(const float4*)(fws + 448 + mi * 16 + q * 4);
            wfy = *(const float4*)(fws + 512 + mi * 16 + q * 4);
        }
#pragma unroll
        for (int ni = 0; ni < 2; ni++) {
            const int nr = 32 * w + ni * 16 + ln;
            float ox = 0.f, oy = 0.f, co = 0.f, fx = 0.f, fy = 0.f;
            if (off_fix) {
                ox = offsp[nr]; oy = offsp[NT + nr];
                co = auxp[nr];  fx = auxp[NT + nr]; fy = auxp[2 * NT + nr];
            }
            float av[4];
#pragma unroll
            for (int r = 0; r < 4; r++) {
                float a = acc[mi][ni][r] + ((const float*)&bias)[r];
                if (off_fix) {
                    a += ((const float*)&wox)[r] * ox + ((const float*)&woy)[r] * oy;
                    a += ((const float*)&wco)[r] * co;
                    a += ((const float*)&wfx)[r] * fx + ((const float*)&wfy)[r] * fy;
                }
                av[r] = fmaxf(a, 0.1f * a);
            }
#pragma unroll
            for (int t = 0; t < 2; t++) {
                const unsigned hh = cvtpk(av[2 * t], av[2 * t + 1]);
                const float l0 = av[2 * t]     - __uint_as_float(hh << 16);
                const float l1 = av[2 * t + 1] - __uint_as_float(hh & 0xffff0000u);
                pkH[mi][ni][t] = hh;
                pkL[mi][ni][t] = cvtpk(l0, l1);
            }
        }
    }
}

// ---------------- main fused kernel: 1 tile/block, 3 blocks/CU, gather-as-B-fragment ------
// LDS = 53,760 B -> 3 blocks/CU (12 waves = 3/SIMD, +50% residency vs R9). Xhi eliminated:
// the gather lands directly in MFMA-B layout, so L1 runs from registers with no LDS hop.
__global__ __launch_bounds__(256, 3) void fuse(
    const float* __restrict__ feat2d, const float* __restrict__ lf2d,
    const int* __restrict__ nn,
    const unsigned short* __restrict__ wpk, const float* __restrict__ fws,
    const char* __restrict__ ptab,
    float* __restrict__ out)
{
    __shared__ unsigned short F2[NT * F2PITCH];   // 18432 B (feat2d tile bf16 [px][ch])
    __shared__ unsigned short Wl[16384];          // 32768 B (W2/W3/WF, swizzled)
    __shared__ float offsS[2 * NT];               //  1024 B
    __shared__ float auxS[3 * NT];                //  1536 B

    const int tid = threadIdx.x;
    const int w = tid >> 6, lane = tid & 63;
    const int q = lane >> 4, ln = lane & 15;
    const int b = blockIdx.y;
    const int p0 = blockIdx.x * NT;

    // bpermute byte addresses for the q-group exchange (src lanes (q&1)*2*16+ln, +16)
    const int srcA = (((lane >> 4) & 1) * 32 + ln) * 4;
    const int srcB = srcA + 64;
    const int qh = q >> 1;
    const int swz = (ln & 7) << 4;

    const int i0 = nn[(size_t)b * HW + p0 + 32 * w + ln];
    const int i1 = nn[(size_t)b * HW + p0 + 32 * w + 16 + ln];

    pref_t P;
    tile_load(P, feat2d, lf2d, ptab, b, p0, w, lane, i0, i1);  // HBM latency hides under wstage
    wstage(wpk, Wl, tid);
    __syncthreads();

    // W1 A-fragments from global (L2-hot; issued early, consumed after corr)
    short8 A1[2][4];
#pragma unroll
    for (int kt = 0; kt < 2; kt++)
#pragma unroll
        for (int mi = 0; mi < 4; mi++)
            A1[kt][mi] = *(const short8*)(wpk + W1OFS + (mi * 16 + ln) * 64 + kt * 32 + q * 8);

    tile_stage(P, F2, w, lane);
    tile_corr(P, F2, offsS, auxS, p0, w, lane, q, ln);

    unsigned int pkH[4][2][2], pkL[4][2][2];
    f32x4 acc[4][2];
    // L1 (K=64, g only; B straight from gather registers; corr/offset/flow via rank-5 f32 fix)
    zero_acc(acc);
#pragma unroll
    for (int kt = 0; kt < 2; kt++) {
#pragma unroll
        for (int ni = 0; ni < 2; ni++) {
            __builtin_amdgcn_s_setprio(1);
#pragma unroll
            for (int mi = 0; mi < 4; mi++)
                acc[mi][ni] = __builtin_amdgcn_mfma_f32_16x16x32_bf16(A1[kt][mi], P.g4[ni][kt].v, acc[mi][ni], 0, 0, 0);
            __builtin_amdgcn_s_setprio(0);
        }
    }
    epi_pack(acc, fws, 0, true, offsS, auxS, pkH, pkL, w, ln, q);
    // L2, L3 (identical structure — rolled)
#pragma unroll 1
    for (int l = 0; l < 2; l++) {
        zero_acc(acc);
        layer_reg<128>(Wl + W2L + (l << 12), pkH, pkL, srcA, srcB, qh, ln, q, swz, acc);
        epi_pack(acc, fws, 64 + (l << 6), false, offsS, auxS, pkH, pkL, w, ln, q);
    }
    // Lf: k 0-63 = x3 (reg exchange, hi+lo), k 64-127 = feat2d tile (F2 LDS, hi only)
    zero_acc(acc);
    layer_reg<256>(Wl + WFL, pkH, pkL, srcA, srcB, qh, ln, q, swz, acc);
#pragma unroll
    for (int kt = 2; kt < 4; kt++) {
        const int kb = (kt * 32 + q * 8) * 2;
        short8 A[4];
#pragma unroll
        for (int mi = 0; mi < 4; mi++)
            A[mi] = *(const short8*)((const char*)(Wl + WFL) + (mi * 16 + ln) * 256 + (kb ^ swz));
#pragma unroll
        for (int ni = 0; ni < 2; ni++) {
            const int nr = 32 * w + ni * 16 + ln;
            frag_u fh;
            fh.v = *(const short8*)&F2[nr * F2PITCH + (kt - 2) * 32 + q * 8];
            __builtin_amdgcn_s_setprio(1);
#pragma unroll
            for (int mi = 0; mi < 4; mi++)
                acc[mi][ni] = __builtin_amdgcn_mfma_f32_16x16x32_bf16(A[mi], fh.v, acc[mi][ni], 0, 0, 0);
            __builtin_amdgcn_s_setprio(0);
        }
    }
    // final epilogue -> out f32
#pragma unroll
    for (int mi = 0; mi < 4; mi++) {
        const float4 bias = *(const float4*)(fws + 192 + mi * 16 + q * 4);
#pragma unroll
        for (int ni = 0; ni < 2; ni++) {
#pragma unroll
            for (int r = 0; r < 4; r++) {
                float a = acc[mi][ni][r] + ((const float*)&bias)[r];
                a = fmaxf(a, 0.1f * a);
                const int m = mi * 16 + q * 4 + r;
                out[(size_t)(b * CH + m) * HW + p0 + 32 * w + ni * 16 + ln] = a;
            }
        }
    }
}

// ---------------- fallback: used only if ws too small ----------------
__global__ __launch_bounds__(256) void fuse_slow(
    const float* __restrict__ feat2d, const float* __restrict__ lf2d,
    const float* __restrict__ xy, const float* __restrict__ feat3d,
    const float* __restrict__ lf3d, const int* __restrict__ nn,
    const float* __restrict__ w1, const float* __restrict__ b1,
    const float* __restrict__ w2, const float* __restrict__ b2,
    const float* __restrict__ w3, const float* __restrict__ b3,
    const float* __restrict__ wf, const float* __restrict__ bfv,
    float* __restrict__ out)
{
    const int p = blockIdx.x * 256 + threadIdx.x;
    const int b = blockIdx.y;
    const int idx = nn[(size_t)b * HW + p];
    const float* f3 = feat3d + (size_t)b * CH * NN + idx;
    float g[CH];
#pragma unroll
    for (int c = 0; c < CH; c++) g[c] = f3[(size_t)c * NN];
    const float fl3x = lf3d[(size_t)(b * 2 + 0) * NN + idx];
    const float fl3y = lf3d[(size_t)(b * 2 + 1) * NN + idx];
    const float xyx = xy[(size_t)(b * 2 + 0) * NN + idx];
    const float xyy = xy[(size_t)(b * 2 + 1) * NN + idx];
    const float* f2p = feat2d + (size_t)b * CH * HW + p;
    float corr = 0.f;
#pragma unroll
    for (int c = 0; c < CH; c++) corr += f2p[(size_t)c * HW] * g[c];
    corr *= (1.f / 64.f);
    float xin[69];
    xin[0] = corr;
    xin[1] = xyx - (float)(p & 255);
    xin[2] = xyy - (float)(p >> 8);
#pragma unroll
    for (int c = 0; c < CH; c++) xin[3 + c] = g[c];
    xin[67] = fl3x - lf2d[(size_t)(b * 2 + 0) * HW + p];
    xin[68] = fl3y - lf2d[(size_t)(b * 2 + 1) * HW + p];
    float x1[64], x2[64], x3[64], accv[64];
#pragma unroll
    for (int o = 0; o < 64; o++) {
        float a = b1[o];
#pragma unroll
        for (int k = 0; k < 69; k++) a += w1[o * 69 + k] * xin[k];
        x1[o] = (a >= 0.f) ? a : 0.1f * a;
    }
#pragma unroll
    for (int o = 0; o < 64; o++) {
        float a = b2[o];
#pragma unroll
        for (int k = 0; k < 64; k++) a += w2[o * 64 + k] * x1[k];
        x2[o] = (a >= 0.f) ? a : 0.1f * a;
    }
#pragma unroll
    for (int o = 0; o < 64; o++) {
        float a = b3[o];
#pragma unroll
        for (int k = 0; k < 64; k++) a += w3[o * 64 + k] * x2[k];
        x3[o] = (a >= 0.f) ? a : 0.1f * a;
    }
#pragma unroll
    for (int o = 0; o < 64; o++) {
        float a = bfv[o];
#pragma unroll
        for (int k = 0; k < 64; k++) a += wf[o * 128 + k] * x3[k];
        accv[o] = a;
    }
#pragma unroll
    for (int k = 0; k < 64; k++) {
        const float f = f2p[(size_t)k * HW];
#pragma unroll
        for (int o = 0; o < 64; o++) accv[o] += wf[o * 128 + 64 + k] * f;
    }
#pragma unroll
    for (int o = 0; o < 64; o++) {
        float a = accv[o];
        a = (a >= 0.f) ? a : 0.1f * a;
        out[(size_t)(b * CH + o) * HW + p] = a;
    }
}

extern "C" void kernel_launch(void* const* d_in, const int* in_sizes, int n_in,
                              void* d_out, int out_size, void* d_ws, size_t ws_size,
                              hipStream_t stream)
{
    const float* xy   = (const float*)d_in[0];
    const float* f2d  = (const float*)d_in[1];
    const float* f3d  = (const float*)d_in[2];
    const float* lf2d = (const float*)d_in[3];
    const float* lf3d = (const float*)d_in[4];
    const int*   nn   = (const int*)d_in[5];
    const float* w1 = (const float*)d_in[6];
    const float* b1 = (const float*)d_in[7];
    const float* w2 = (const float*)d_in[8];
    const float* b2 = (const float*)d_in[9];
    const float* w3 = (const float*)d_in[10];
    const float* b3 = (const float*)d_in[11];
    const float* wf = (const float*)d_in[12];
    const float* bf = (const float*)d_in[13];

    if (ws_size >= WS_NEED) {
        unsigned short* wpk = (unsigned short*)d_ws;
        float* fws = (float*)((char*)d_ws + FWS_BYTE);
        char* pt = (char*)d_ws + PTAB_BYTE;
        prep<<<dim3(NN / 64 + 5, BB), 256, 0, stream>>>(xy, f3d, lf3d,
                                                        w1, b1, w2, b2, w3, b3, wf, bf,
                                                        wpk, fws, pt);
        fuse<<<dim3(HW / NT, BB), 256, 0, stream>>>(f2d, lf2d, nn, wpk, fws, pt, (float*)d_out);
    } else {
        fuse_slow<<<dim3(HW / 256, BB), 256, 0, stream>>>(f2d, lf2d, xy, f3d, lf3d, nn,
                                                          w1, b1, w2, b2, w3, b3, wf, bf,
                                                          (float*)d_out);
    }
}